// Round 1
// baseline (400.491 us; speedup 1.0000x reference)
//
#include <hip/hip_runtime.h>

// ---------------------------------------------------------------------------
// GCN forward. Evidence-driven design (R4-R15 + this round R16):
//  - GEMMs on MFMA (16x16x32 bf16): W staged in LDS pre-swizzled to B-frag
//    layout; A-frag = one 16B bf16 load; C/D: row=(lane>>4)*4+reg, col=lane&15.
//    K padded to 128; zeroed W pad rows neutralize garbage in A pad cols.
//  - R16: aggregation is the dominant cost (~a*instrs + b*lines, and lines
//    came from L3: 205MB random gather over a 12.8MB H that can't fit a 4MiB
//    per-XCD L2). H is now stored in COLUMN PLANES of 32 feats (64B rows,
//    3.2MB/plane -> L2-resident), and agg blocks are pinned to the XCD owning
//    their plane via the blockIdx%8 round-robin mapping. epack edge stream is
//    nontemporal so it doesn't evict the plane. Pad lanes early-return
//    (old code gathered pad cols 100..127 for every edge).
//  - agg: single pass, 4 lanes x uint4 per node-slice (8 feats/lane),
//    degree-sorted perm; ONE packed 32-bit atomic per edge (count<<24|wsum
//    fix16); returned rank makes CSR fill atomic-free.
//  - edge (col,norm) packed i64; NT stores via ext_vector.
// ---------------------------------------------------------------------------

#define BT 256
#define SCAN_B 256

typedef float nfloat4 __attribute__((ext_vector_type(4)));
typedef float nfloat2 __attribute__((ext_vector_type(2)));
typedef unsigned int nuint4 __attribute__((ext_vector_type(4)));
typedef __attribute__((ext_vector_type(8))) short shortx8;   // 8 bf16 (A/B frag)
typedef __attribute__((ext_vector_type(4))) float floatx4;   // C/D frag

__device__ inline float bf_lo(unsigned int v) { return __uint_as_float(v << 16); }
__device__ inline float bf_hi(unsigned int v) { return __uint_as_float(v & 0xFFFF0000u); }
__device__ inline unsigned short f2bf(float f) {  // round-to-nearest-even
    unsigned int u = __float_as_uint(f);
    unsigned int r = u + 0x7FFFu + ((u >> 16) & 1u);
    return (unsigned short)(r >> 16);
}

// ---------------- precompute ----------------
__global__ void zero_kernel(unsigned int* buf, int n) {
    int i = blockIdx.x * blockDim.x + threadIdx.x;
    if (i < n) buf[i] = 0u;
}

__global__ void hist_kernel(const int* __restrict__ row, const float* __restrict__ w,
                            unsigned int* cw, int* __restrict__ rank, int e) {
    int i = blockIdx.x * blockDim.x + threadIdx.x;
    if (i >= e) return;
    unsigned int wq = (unsigned int)(w[i] * 65536.0f + 0.5f);
    unsigned int old = atomicAdd(&cw[row[i]], (1u << 24) | wq);
    rank[i] = (int)(old >> 24);
}

// FUSED: block-scan of counts + dis + hierarchical degree histogram
__global__ __launch_bounds__(SCAN_B) void nodeprep_kernel(const unsigned int* __restrict__ cw,
                                                          int* rowptr, int* bsums, float* dis,
                                                          int* dbin, int* __restrict__ nrank,
                                                          int n) {
    __shared__ int s[SCAN_B];
    __shared__ int lbin[256];
    __shared__ int lbase[256];
    const int t = threadIdx.x;
    const int i = blockIdx.x * SCAN_B + t;
    unsigned int cv = (i < n) ? cw[i] : 0u;
    const int v = (int)(cv >> 24);
    lbin[t] = 0;
    s[t] = v;
    __syncthreads();
    int lr = 0;
    if (i < n) lr = atomicAdd(&lbin[v], 1);
    __syncthreads();
    for (int off = 1; off < SCAN_B; off <<= 1) {
        int x = (t >= off) ? s[t - off] : 0;
        __syncthreads();
        s[t] += x;
        __syncthreads();
    }
    if (i < n) {
        rowptr[i] = s[t] - v;
        float d = 1.0f + (float)(cv & 0xFFFFFFu) * (1.0f / 65536.0f);
        dis[i] = rsqrtf(fmaxf(d, 1e-12f));
    }
    if (t == SCAN_B - 1) bsums[blockIdx.x] = s[t];
    int c = lbin[t];
    lbase[t] = (c > 0) ? atomicAdd(&dbin[t], c) : 0;
    __syncthreads();
    if (i < n) nrank[i] = lbase[v] + lr;
}

__global__ __launch_bounds__(256) void scan2both_kernel(int* bsums, int nb, int* dbin) {
    __shared__ int s[256];
    const int t = threadIdx.x;
    int v = (t < nb) ? bsums[t] : 0;
    s[t] = v;
    __syncthreads();
    for (int off = 1; off < 256; off <<= 1) {
        int x = (t >= off) ? s[t - off] : 0;
        __syncthreads();
        s[t] += x;
        __syncthreads();
    }
    if (t < nb) bsums[t] = s[t] - v;
    __syncthreads();
    int v2 = dbin[t];
    s[t] = v2;
    __syncthreads();
    for (int off = 1; off < 256; off <<= 1) {
        int x = (t >= off) ? s[t - off] : 0;
        __syncthreads();
        s[t] += x;
        __syncthreads();
    }
    dbin[t] = s[t] - v2;
}

__global__ void scan3_kernel(int* rowptr, const int* __restrict__ bsums,
                             const unsigned int* __restrict__ cw,
                             const int* __restrict__ nrank, const int* __restrict__ dbin,
                             int* __restrict__ perm, int n, int e) {
    int i = blockIdx.x * blockDim.x + threadIdx.x;
    if (i < n) {
        rowptr[i] += bsums[i / SCAN_B];
        unsigned int deg = cw[i] >> 24;
        perm[dbin[deg] + nrank[i]] = i;
    }
    if (i == 0) rowptr[n] = e;
}

__global__ void fill_kernel(const int* __restrict__ row, const int* __restrict__ col,
                            const float* __restrict__ w, const float* __restrict__ dis,
                            const int* __restrict__ rowptr, const int* __restrict__ rank,
                            long long* __restrict__ epack, int e) {
    int i = blockIdx.x * blockDim.x + threadIdx.x;
    if (i >= e) return;
    int r = row[i], c = col[i];
    float nv = dis[r] * w[i] * dis[c];
    int dst = rowptr[r] + rank[i];
    long long v = ((long long)__float_as_int(nv) << 32) | (unsigned int)c;
    __builtin_nontemporal_store(v, &epack[dst]);
}

// ---------------- MFMA GEMM: H = X @ W, output bf16 ------------------------
// SLICED=true: H stored as column planes of 32 feats: H[(c>>5)*n*32 + row*32
// + (c&31)] -> each plane is n*64B (3.2MB), L2-resident for the agg gather.
template <int KREAL, int KPAD, int F, bool IN_BF16, int INS, int OUTS, bool SLICED>
__global__ __launch_bounds__(256) void gemm_mfma_kernel(const void* __restrict__ Xv,
                                                        const float* __restrict__ W,
                                                        unsigned short* __restrict__ H, int n) {
    constexpr int KS = KPAD / 32;
    constexpr int NT = (F + 15) / 16;
    __shared__ unsigned short Wf[KS * NT * 64 * 8];
    const int tid = threadIdx.x;
    for (int i = tid; i < KS * NT * 64 * 8; i += 256) {
        int j = i & 7;
        int ln = (i >> 3) & 63;
        int rest = i >> 9;
        int nt = rest % NT;
        int ks = rest / NT;
        int k = ks * 32 + ((ln >> 4) << 3) + j;
        int c = nt * 16 + (ln & 15);
        float wv = (k < KREAL && c < F) ? W[k * F + c] : 0.f;
        Wf[i] = f2bf(wv);
    }
    __syncthreads();

    const int wid = tid >> 6;
    const int lane = tid & 63;
    const int m = lane & 15;
    const int q = lane >> 4;
    const int r0 = blockIdx.x * 64 + wid * 16;
    int rowc = r0 + m;
    if (rowc > n - 1) rowc = n - 1;  // clamp loads; stores guarded

    floatx4 acc[NT];
#pragma unroll
    for (int nt = 0; nt < NT; ++nt) acc[nt] = (floatx4){0.f, 0.f, 0.f, 0.f};

    const float* Xf = (const float*)Xv;
    const unsigned short* Xb = (const unsigned short*)Xv;
#pragma unroll
    for (int ks = 0; ks < KS; ++ks) {
        shortx8 af;
        if constexpr (IN_BF16) {
            af = *(const shortx8*)&Xb[(size_t)rowc * INS + ks * 32 + q * 8];
        } else {
            const float* xp = &Xf[(size_t)rowc * INS + ks * 32 + q * 8];
            float4 xa = *(const float4*)xp;
            float4 xc = *(const float4*)(xp + 4);
            union { shortx8 s; unsigned int u[4]; } cv;
            cv.u[0] = ((unsigned int)f2bf(xa.y) << 16) | f2bf(xa.x);
            cv.u[1] = ((unsigned int)f2bf(xa.w) << 16) | f2bf(xa.z);
            cv.u[2] = ((unsigned int)f2bf(xc.y) << 16) | f2bf(xc.x);
            cv.u[3] = ((unsigned int)f2bf(xc.w) << 16) | f2bf(xc.z);
            af = cv.s;
        }
#pragma unroll
        for (int nt = 0; nt < NT; ++nt) {
            shortx8 bf = *(const shortx8*)&Wf[(((ks * NT) + nt) * 64 + lane) * 8];
            acc[nt] = __builtin_amdgcn_mfma_f32_16x16x32_bf16(af, bf, acc[nt], 0, 0, 0);
        }
    }

#pragma unroll
    for (int nt = 0; nt < NT; ++nt) {
        int c = nt * 16 + m;
        if (c >= F) continue;
#pragma unroll
        for (int r = 0; r < 4; ++r) {
            int orow = r0 + q * 4 + r;
            if (orow < n) {
                if constexpr (SLICED) {
                    H[((size_t)(c >> 5) * n + orow) * 32 + (c & 31)] = f2bf(acc[nt][r]);
                } else {
                    H[(size_t)orow * OUTS + c] = f2bf(acc[nt][r]);
                }
            }
        }
    }
}

// thread-per-row GEMV for tiny F (layer 3: K=50, F=6), fp32 out stride FS.
template <int K, int F, int FS, bool RELU_IN>
__global__ __launch_bounds__(256) void gemv_rows_kernel(const float* __restrict__ X,
                                                        const float* __restrict__ W,
                                                        float* __restrict__ H, int n) {
    static_assert(K % 2 == 0, "K must be even");
    __shared__ float Ws[K * F];
    const int tid = threadIdx.x;
    for (int i = tid; i < K * F; i += 256) Ws[i] = W[i];
    __syncthreads();
    int r = blockIdx.x * 256 + tid;
    if (r >= n) return;
    float acc[F] = {};
    const float* xp = X + (long long)r * K;
    for (int k = 0; k < K; k += 2) {
        float2 x2 = *reinterpret_cast<const float2*>(xp + k);
        if (RELU_IN) { x2.x = fmaxf(x2.x, 0.f); x2.y = fmaxf(x2.y, 0.f); }
#pragma unroll
        for (int j = 0; j < F; ++j)
            acc[j] += x2.x * Ws[k * F + j] + x2.y * Ws[(k + 1) * F + j];
    }
    long long base = (long long)r * FS;
#pragma unroll
    for (int j = 0; j < F; ++j) H[base + j] = acc[j];
}

// ---------------- feature-sliced single-pass agg ---------------------------
// H is in NSLICE column planes of 32 feats (64B rows, plane = n*64B, fits a
// 4MiB per-XCD L2). Block -> XCD via blockIdx%8 (measured round-robin);
// slice = xcd/XPS so each XCD only gathers from its own L2-resident plane.
// 4 lanes x uint4 per node-slice. epack loaded nontemporal (stream; don't
// evict the plane). Pad lanes (f>=F) early-return: next GEMM's zeroed W pad
// rows neutralize whatever is left in A's pad cols.
// OUT_BF16=true : A bf16 rows (RSOUT ushorts) with fused ReLU (feeds MFMA).
// OUT_BF16=false: A fp32 rows (RSOUT floats), no ReLU (feeds gemv, RELU_IN).
template <int F, int NSLICE, int RSOUT, bool OUT_BF16>
__global__ __launch_bounds__(BT) void agg_sl_kernel(const int* __restrict__ rowptr,
                                                    const int* __restrict__ perm,
                                                    const long long* __restrict__ epack,
                                                    const uint4* __restrict__ H,
                                                    const float* __restrict__ dis,
                                                    const float* __restrict__ bias,
                                                    void* __restrict__ Aout, int n) {
    constexpr int LPS = 4;                 // lanes per node-slice (4 x 16B = 32 feats)
    constexpr int NPB = BT / LPS;          // 64 node-slices per block
    constexpr int XPS = 8 / NSLICE;        // XCDs per slice
    const int b = blockIdx.x;
    const int xcd = b & 7;
    const int slice = xcd / XPS;
    const int pb = (b >> 3) * XPS + (xcd & (XPS - 1));
    const int sidx = pb * NPB + (int)(threadIdx.x >> 2);
    const int lane = threadIdx.x & 3;
    if (sidx >= n) return;
    const int f = slice * 32 + lane * 8;
    if (f >= F) return;
    const int node = perm[sidx];
    const uint4* __restrict__ Hp = H + (size_t)slice * n * 4;  // plane base (uint4 units)

    float a[8] = {};
    int j = rowptr[node];
    const int end = rowptr[node + 1];
    for (; j + 4 <= end; j += 4) {
        long long e0 = __builtin_nontemporal_load(&epack[j + 0]);
        long long e1 = __builtin_nontemporal_load(&epack[j + 1]);
        long long e2 = __builtin_nontemporal_load(&epack[j + 2]);
        long long e3 = __builtin_nontemporal_load(&epack[j + 3]);
        uint4 v0 = Hp[(size_t)(int)e0 * 4 + lane];
        uint4 v1 = Hp[(size_t)(int)e1 * 4 + lane];
        uint4 v2 = Hp[(size_t)(int)e2 * 4 + lane];
        uint4 v3 = Hp[(size_t)(int)e3 * 4 + lane];
        float n0 = __int_as_float((int)(e0 >> 32));
        float n1 = __int_as_float((int)(e1 >> 32));
        float n2 = __int_as_float((int)(e2 >> 32));
        float n3 = __int_as_float((int)(e3 >> 32));
        a[0] += n0 * bf_lo(v0.x); a[1] += n0 * bf_hi(v0.x);
        a[2] += n0 * bf_lo(v0.y); a[3] += n0 * bf_hi(v0.y);
        a[4] += n0 * bf_lo(v0.z); a[5] += n0 * bf_hi(v0.z);
        a[6] += n0 * bf_lo(v0.w); a[7] += n0 * bf_hi(v0.w);
        a[0] += n1 * bf_lo(v1.x); a[1] += n1 * bf_hi(v1.x);
        a[2] += n1 * bf_lo(v1.y); a[3] += n1 * bf_hi(v1.y);
        a[4] += n1 * bf_lo(v1.z); a[5] += n1 * bf_hi(v1.z);
        a[6] += n1 * bf_lo(v1.w); a[7] += n1 * bf_hi(v1.w);
        a[0] += n2 * bf_lo(v2.x); a[1] += n2 * bf_hi(v2.x);
        a[2] += n2 * bf_lo(v2.y); a[3] += n2 * bf_hi(v2.y);
        a[4] += n2 * bf_lo(v2.z); a[5] += n2 * bf_hi(v2.z);
        a[6] += n2 * bf_lo(v2.w); a[7] += n2 * bf_hi(v2.w);
        a[0] += n3 * bf_lo(v3.x); a[1] += n3 * bf_hi(v3.x);
        a[2] += n3 * bf_lo(v3.y); a[3] += n3 * bf_hi(v3.y);
        a[4] += n3 * bf_lo(v3.z); a[5] += n3 * bf_hi(v3.z);
        a[6] += n3 * bf_lo(v3.w); a[7] += n3 * bf_hi(v3.w);
    }
    for (; j < end; ++j) {
        long long ev = __builtin_nontemporal_load(&epack[j]);
        uint4 v = Hp[(size_t)(int)ev * 4 + lane];
        float nv = __int_as_float((int)(ev >> 32));
        a[0] += nv * bf_lo(v.x); a[1] += nv * bf_hi(v.x);
        a[2] += nv * bf_lo(v.y); a[3] += nv * bf_hi(v.y);
        a[4] += nv * bf_lo(v.z); a[5] += nv * bf_hi(v.z);
        a[6] += nv * bf_lo(v.w); a[7] += nv * bf_hi(v.w);
    }

    const int valid = F - f;  // >=1 here
    float d = dis[node];
    float d2 = d * d;
    uint4 hs = Hp[(size_t)node * 4 + lane];
    float h[8] = {bf_lo(hs.x), bf_hi(hs.x), bf_lo(hs.y), bf_hi(hs.y),
                  bf_lo(hs.z), bf_hi(hs.z), bf_lo(hs.w), bf_hi(hs.w)};
    if constexpr (OUT_BF16) {
        unsigned short* A = (unsigned short*)Aout;
        unsigned short o[8];
#pragma unroll
        for (int k = 0; k < 8; ++k) {
            float t = (k < valid) ? fmaxf(bias[f + k] + d2 * h[k] + a[k], 0.f) : 0.f;
            o[k] = f2bf(t);
        }
        nuint4 qv;
        qv.x = ((unsigned int)o[1] << 16) | o[0];
        qv.y = ((unsigned int)o[3] << 16) | o[2];
        qv.z = ((unsigned int)o[5] << 16) | o[4];
        qv.w = ((unsigned int)o[7] << 16) | o[6];
        __builtin_nontemporal_store(qv, (nuint4*)&A[(size_t)node * RSOUT + f]);
    } else {
        float* A = (float*)Aout;
        float o[8];
#pragma unroll
        for (int k = 0; k < 8; ++k)
            o[k] = (k < valid) ? (bias[f + k] + d2 * h[k] + a[k]) : 0.f;
        float* ap = &A[(size_t)node * RSOUT + f];
        if (valid >= 8) {
            nfloat4 q0 = {o[0], o[1], o[2], o[3]};
            nfloat4 q1 = {o[4], o[5], o[6], o[7]};
            __builtin_nontemporal_store(q0, (nfloat4*)ap);
            __builtin_nontemporal_store(q1, (nfloat4*)(ap + 4));
        } else if (valid >= 4) {
            nfloat4 q0 = {o[0], o[1], o[2], o[3]};
            __builtin_nontemporal_store(q0, (nfloat4*)ap);
        } else if (valid >= 2) {
            nfloat2 q = {o[0], o[1]};
            __builtin_nontemporal_store(q, (nfloat2*)ap);
        } else {
            __builtin_nontemporal_store(o[0], ap);
        }
    }
}

// per-node agg for tiny F (fp32 H, row stride 8), degree-sorted. H3 = 1.6MB,
// naturally L2-resident per XCD - no slicing needed.
template <int F, int TPN>
__global__ __launch_bounds__(BT) void agg_small_kernel(const int* __restrict__ rowptr,
                                                       const int* __restrict__ perm,
                                                       const long long* __restrict__ epack,
                                                       const float* __restrict__ H,
                                                       const float* __restrict__ dis,
                                                       const float* __restrict__ bias,
                                                       float* __restrict__ A, int n) {
    int gid = blockIdx.x * blockDim.x + threadIdx.x;
    int sidx = gid / TPN;
    int lane = threadIdx.x & (TPN - 1);
    if (sidx >= n) return;
    int node = perm[sidx];
    bool active = (lane < F);
    float acc = 0.f;
    int j = rowptr[node];
    const int end = rowptr[node + 1];
    for (; j + 4 <= end; j += 4) {
        long long e0 = epack[j + 0];
        long long e1 = epack[j + 1];
        long long e2 = epack[j + 2];
        long long e3 = epack[j + 3];
        if (active) {
            float h0 = H[(size_t)(int)e0 * 8 + lane];
            float h1 = H[(size_t)(int)e1 * 8 + lane];
            float h2 = H[(size_t)(int)e2 * 8 + lane];
            float h3 = H[(size_t)(int)e3 * 8 + lane];
            acc += __int_as_float((int)(e0 >> 32)) * h0;
            acc += __int_as_float((int)(e1 >> 32)) * h1;
            acc += __int_as_float((int)(e2 >> 32)) * h2;
            acc += __int_as_float((int)(e3 >> 32)) * h3;
        }
    }
    for (; j < end; ++j) {
        long long ev = epack[j];
        if (active) acc += __int_as_float((int)(ev >> 32)) * H[(size_t)(int)ev * 8 + lane];
    }
    if (active) {
        float d = dis[node];
        float v = bias[lane] + d * d * H[(size_t)node * 8 + lane] + acc;
        __builtin_nontemporal_store(v, &A[(size_t)node * F + lane]);
    }
}

// ---------------------------------------------------------------------------
extern "C" void kernel_launch(void* const* d_in, const int* in_sizes, int n_in,
                              void* d_out, int out_size, void* d_ws, size_t ws_size,
                              hipStream_t stream) {
    const float* x  = (const float*)d_in[0];
    const int*   ei = (const int*)d_in[1];
    const float* ew = (const float*)d_in[2];
    const float* W0 = (const float*)d_in[3];
    const float* b0 = (const float*)d_in[4];
    const float* W1 = (const float*)d_in[5];
    const float* b1 = (const float*)d_in[6];
    const float* W2 = (const float*)d_in[7];
    const float* b2 = (const float*)d_in[8];
    const float* W3 = (const float*)d_in[9];
    const float* b3 = (const float*)d_in[10];
    float* out = (float*)d_out;

    const int N = in_sizes[0] / 128;  // 50000
    const int E = in_sizes[1] / 2;    // 800000
    const int* row = ei;
    const int* col = ei + E;

    const int NB = (N + SCAN_B - 1) / SCAN_B;
    const int blocksN = (N + BT - 1) / BT;
    const int blocksE = (E + BT - 1) / BT;

    // workspace, 64B-aligned sections
    char* p = (char*)d_ws;
    auto alloc = [&](size_t bytes) {
        p = (char*)(((uintptr_t)p + 63) & ~(uintptr_t)63);
        void* r = (void*)p;
        p += bytes;
        return r;
    };
    float* dis    = (float*)alloc((size_t)N * 4);
    int*   rowptr = (int*)alloc((size_t)(N + 2) * 4);
    int*   bsums  = (int*)alloc(SCAN_B * 4);
    unsigned int* cw = (unsigned int*)alloc((size_t)(N + 256) * 4);  // cw[N] + dbin[256]
    int*   dbin   = (int*)(cw + N);
    int*   nrank  = (int*)alloc((size_t)N * 4);
    int*   perm   = (int*)alloc((size_t)N * 4);
    int*   rank   = (int*)alloc((size_t)E * 4);
    long long* epack = (long long*)alloc((size_t)E * 8);
    unsigned short* bufA = (unsigned short*)alloc((size_t)N * 128 * 2);  // H planes (bf16)
    unsigned short* bufB = (unsigned short*)alloc((size_t)N * 128 * 2);  // A bf16 / A3 fp32
    float* bufAf  = (float*)bufA;  // layer-3 fp32 H3[N,8] aliases bufA
    float* bufBf  = (float*)bufB;  // layer-3 fp32 A3[N,50] aliases bufB

    // ---- CSR + norm + degree-sort precompute ----
    zero_kernel<<<(N + 256 + BT - 1) / BT, BT, 0, stream>>>(cw, N + 256);
    hist_kernel<<<blocksE, BT, 0, stream>>>(row, ew, cw, rank, E);
    nodeprep_kernel<<<NB, SCAN_B, 0, stream>>>(cw, rowptr, bsums, dis, dbin, nrank, N);
    scan2both_kernel<<<1, 256, 0, stream>>>(bsums, NB, dbin);
    scan3_kernel<<<blocksN, BT, 0, stream>>>(rowptr, bsums, cw, nrank, dbin, perm, N, E);
    fill_kernel<<<blocksE, BT, 0, stream>>>(row, col, ew, dis, rowptr, rank, epack, E);

    const int gemm_blocks = (N + 63) / 64;        // 64 rows/block (4 waves x 16)
    const int Bs = (N + 63) / 64;                 // 64 node-slices/block -> 782
    const int grid_sl4 = 8 * ((Bs + 1) / 2);      // 4 slices, 2 XCDs each -> 3128
    const int grid_sl2 = 8 * ((Bs + 3) / 4);      // 2 slices, 4 XCDs each -> 1568
    const int agg6_blocks = (N * 8 + BT - 1) / BT;

    // ---- layer 0: x fp32 (K=128) -> H planes bf16 (4 x 32 cols) ----
    gemm_mfma_kernel<128, 128, 100, false, 128, 128, true><<<gemm_blocks, 256, 0, stream>>>(x, W0, bufA, N);
    agg_sl_kernel<100, 4, 128, true><<<grid_sl4, BT, 0, stream>>>(rowptr, perm, epack, (const uint4*)bufA, dis, b0, bufB, N);

    // ---- layer 1: A1 bf16 rows (K=100 pad 128) -> H planes ----
    gemm_mfma_kernel<100, 128, 100, true, 128, 128, true><<<gemm_blocks, 256, 0, stream>>>(bufB, W1, bufA, N);
    agg_sl_kernel<100, 4, 128, true><<<grid_sl4, BT, 0, stream>>>(rowptr, perm, epack, (const uint4*)bufA, dis, b1, bufB, N);

    // ---- layer 2: A2 bf16 -> H planes (2 x 32 cols), agg to fp32 A3[N,50] ----
    gemm_mfma_kernel<100, 128, 50, true, 128, 64, true><<<gemm_blocks, 256, 0, stream>>>(bufB, W2, bufA, N);
    agg_sl_kernel<50, 2, 50, false><<<grid_sl2, BT, 0, stream>>>(rowptr, perm, epack, (const uint4*)bufA, dis, b2, bufBf, N);

    // ---- layer 3: gemv (relu on load) + small agg ----
    gemv_rows_kernel<50, 6, 8, true><<<(N + 255) / 256, 256, 0, stream>>>(bufBf, W3, bufAf, N);
    agg_small_kernel<6, 8><<<agg6_blocks, BT, 0, stream>>>(rowptr, perm, epack, bufAf, dis, b3, out, N);
}

// Round 3
// 350.762 us; speedup vs baseline: 1.1418x; 1.1418x over previous
//
#include <hip/hip_runtime.h>

// ---------------------------------------------------------------------------
// GCN forward. Evidence-driven design (R4-R17):
//  - GEMMs on MFMA (16x16x32 bf16): W staged in LDS pre-swizzled to B-frag
//    layout; A-frag = one 16B bf16 load; C/D: row=(lane>>4)*4+reg, col=lane&15.
//    K padded to 128; zeroed W pad rows neutralize garbage in A pad cols.
//  - R16 POST-MORTEM: feature-sliced H (4 x 64B planes, XCD-pinned) REGRESSED
//    333->400us. Counters: agg 59us, FETCH 77MB, VALUBusy 13%, hbm 19% ->
//    latency-bound AND line-traffic doubled (4 half-used 128B lines/edge vs
//    2 full ones; cost ~ lines touched). 256B-aligned rows are already at the
//    4-sector/edge floor for 100 bf16 cols. REVERTED.
//  - R17: attack latency + waste instead: (a) pad lanes (f>=F) early-return
//    BEFORE the gather loop (R15 ran the full loop on 3/16 dead lanes),
//    (b) 8-deep edge gather pipeline (was 4) for 2x memory-level parallelism,
//    (c) keep nontemporal epack loads (stream; don't evict H rows from L2).
//    (R18: resubmit unchanged - R17 bench was an infra double-failure.)
//  - agg: single pass, 256B bf16 rows, TPN=16 x uint4 (8 feats/lane);
//    degree-sorted perm (hierarchical LDS histogram).
//  - ONE packed 32-bit atomic per edge (count<<24|wsum fix16); returned rank
//    makes CSR fill atomic-free. edge (col,norm) packed i64; NT stores.
// ---------------------------------------------------------------------------

#define BT 256
#define SCAN_B 256

typedef float nfloat4 __attribute__((ext_vector_type(4)));
typedef float nfloat2 __attribute__((ext_vector_type(2)));
typedef unsigned int nuint4 __attribute__((ext_vector_type(4)));
typedef __attribute__((ext_vector_type(8))) short shortx8;   // 8 bf16 (A/B frag)
typedef __attribute__((ext_vector_type(4))) float floatx4;   // C/D frag

__device__ inline float bf_lo(unsigned int v) { return __uint_as_float(v << 16); }
__device__ inline float bf_hi(unsigned int v) { return __uint_as_float(v & 0xFFFF0000u); }
__device__ inline unsigned short f2bf(float f) {  // round-to-nearest-even
    unsigned int u = __float_as_uint(f);
    unsigned int r = u + 0x7FFFu + ((u >> 16) & 1u);
    return (unsigned short)(r >> 16);
}

// ---------------- precompute ----------------
__global__ void zero_kernel(unsigned int* buf, int n) {
    int i = blockIdx.x * blockDim.x + threadIdx.x;
    if (i < n) buf[i] = 0u;
}

__global__ void hist_kernel(const int* __restrict__ row, const float* __restrict__ w,
                            unsigned int* cw, int* __restrict__ rank, int e) {
    int i = blockIdx.x * blockDim.x + threadIdx.x;
    if (i >= e) return;
    unsigned int wq = (unsigned int)(w[i] * 65536.0f + 0.5f);
    unsigned int old = atomicAdd(&cw[row[i]], (1u << 24) | wq);
    rank[i] = (int)(old >> 24);
}

// FUSED: block-scan of counts + dis + hierarchical degree histogram
__global__ __launch_bounds__(SCAN_B) void nodeprep_kernel(const unsigned int* __restrict__ cw,
                                                          int* rowptr, int* bsums, float* dis,
                                                          int* dbin, int* __restrict__ nrank,
                                                          int n) {
    __shared__ int s[SCAN_B];
    __shared__ int lbin[256];
    __shared__ int lbase[256];
    const int t = threadIdx.x;
    const int i = blockIdx.x * SCAN_B + t;
    unsigned int cv = (i < n) ? cw[i] : 0u;
    const int v = (int)(cv >> 24);
    lbin[t] = 0;
    s[t] = v;
    __syncthreads();
    int lr = 0;
    if (i < n) lr = atomicAdd(&lbin[v], 1);
    __syncthreads();
    for (int off = 1; off < SCAN_B; off <<= 1) {
        int x = (t >= off) ? s[t - off] : 0;
        __syncthreads();
        s[t] += x;
        __syncthreads();
    }
    if (i < n) {
        rowptr[i] = s[t] - v;
        float d = 1.0f + (float)(cv & 0xFFFFFFu) * (1.0f / 65536.0f);
        dis[i] = rsqrtf(fmaxf(d, 1e-12f));
    }
    if (t == SCAN_B - 1) bsums[blockIdx.x] = s[t];
    int c = lbin[t];
    lbase[t] = (c > 0) ? atomicAdd(&dbin[t], c) : 0;
    __syncthreads();
    if (i < n) nrank[i] = lbase[v] + lr;
}

__global__ __launch_bounds__(256) void scan2both_kernel(int* bsums, int nb, int* dbin) {
    __shared__ int s[256];
    const int t = threadIdx.x;
    int v = (t < nb) ? bsums[t] : 0;
    s[t] = v;
    __syncthreads();
    for (int off = 1; off < 256; off <<= 1) {
        int x = (t >= off) ? s[t - off] : 0;
        __syncthreads();
        s[t] += x;
        __syncthreads();
    }
    if (t < nb) bsums[t] = s[t] - v;
    __syncthreads();
    int v2 = dbin[t];
    s[t] = v2;
    __syncthreads();
    for (int off = 1; off < 256; off <<= 1) {
        int x = (t >= off) ? s[t - off] : 0;
        __syncthreads();
        s[t] += x;
        __syncthreads();
    }
    dbin[t] = s[t] - v2;
}

__global__ void scan3_kernel(int* rowptr, const int* __restrict__ bsums,
                             const unsigned int* __restrict__ cw,
                             const int* __restrict__ nrank, const int* __restrict__ dbin,
                             int* __restrict__ perm, int n, int e) {
    int i = blockIdx.x * blockDim.x + threadIdx.x;
    if (i < n) {
        rowptr[i] += bsums[i / SCAN_B];
        unsigned int deg = cw[i] >> 24;
        perm[dbin[deg] + nrank[i]] = i;
    }
    if (i == 0) rowptr[n] = e;
}

__global__ void fill_kernel(const int* __restrict__ row, const int* __restrict__ col,
                            const float* __restrict__ w, const float* __restrict__ dis,
                            const int* __restrict__ rowptr, const int* __restrict__ rank,
                            long long* __restrict__ epack, int e) {
    int i = blockIdx.x * blockDim.x + threadIdx.x;
    if (i >= e) return;
    int r = row[i], c = col[i];
    float nv = dis[r] * w[i] * dis[c];
    int dst = rowptr[r] + rank[i];
    long long v = ((long long)__float_as_int(nv) << 32) | (unsigned int)c;
    __builtin_nontemporal_store(v, &epack[dst]);
}

// ---------------- MFMA GEMM: H(bf16, OUTS-stride rows) = X @ W --------------
template <int KREAL, int KPAD, int F, bool IN_BF16, int INS, int OUTS>
__global__ __launch_bounds__(256) void gemm_mfma_kernel(const void* __restrict__ Xv,
                                                        const float* __restrict__ W,
                                                        unsigned short* __restrict__ H, int n) {
    constexpr int KS = KPAD / 32;
    constexpr int NT = (F + 15) / 16;
    __shared__ unsigned short Wf[KS * NT * 64 * 8];
    const int tid = threadIdx.x;
    for (int i = tid; i < KS * NT * 64 * 8; i += 256) {
        int j = i & 7;
        int ln = (i >> 3) & 63;
        int rest = i >> 9;
        int nt = rest % NT;
        int ks = rest / NT;
        int k = ks * 32 + ((ln >> 4) << 3) + j;
        int c = nt * 16 + (ln & 15);
        float wv = (k < KREAL && c < F) ? W[k * F + c] : 0.f;
        Wf[i] = f2bf(wv);
    }
    __syncthreads();

    const int wid = tid >> 6;
    const int lane = tid & 63;
    const int m = lane & 15;
    const int q = lane >> 4;
    const int r0 = blockIdx.x * 64 + wid * 16;
    int rowc = r0 + m;
    if (rowc > n - 1) rowc = n - 1;  // clamp loads; stores guarded

    floatx4 acc[NT];
#pragma unroll
    for (int nt = 0; nt < NT; ++nt) acc[nt] = (floatx4){0.f, 0.f, 0.f, 0.f};

    const float* Xf = (const float*)Xv;
    const unsigned short* Xb = (const unsigned short*)Xv;
#pragma unroll
    for (int ks = 0; ks < KS; ++ks) {
        shortx8 af;
        if constexpr (IN_BF16) {
            af = *(const shortx8*)&Xb[(size_t)rowc * INS + ks * 32 + q * 8];
        } else {
            const float* xp = &Xf[(size_t)rowc * INS + ks * 32 + q * 8];
            float4 xa = *(const float4*)xp;
            float4 xc = *(const float4*)(xp + 4);
            union { shortx8 s; unsigned int u[4]; } cv;
            cv.u[0] = ((unsigned int)f2bf(xa.y) << 16) | f2bf(xa.x);
            cv.u[1] = ((unsigned int)f2bf(xa.w) << 16) | f2bf(xa.z);
            cv.u[2] = ((unsigned int)f2bf(xc.y) << 16) | f2bf(xc.x);
            cv.u[3] = ((unsigned int)f2bf(xc.w) << 16) | f2bf(xc.z);
            af = cv.s;
        }
#pragma unroll
        for (int nt = 0; nt < NT; ++nt) {
            shortx8 bf = *(const shortx8*)&Wf[(((ks * NT) + nt) * 64 + lane) * 8];
            acc[nt] = __builtin_amdgcn_mfma_f32_16x16x32_bf16(af, bf, acc[nt], 0, 0, 0);
        }
    }

#pragma unroll
    for (int nt = 0; nt < NT; ++nt) {
        int c = nt * 16 + m;
        if (c >= F) continue;
#pragma unroll
        for (int r = 0; r < 4; ++r) {
            int orow = r0 + q * 4 + r;
            if (orow < n) H[(size_t)orow * OUTS + c] = f2bf(acc[nt][r]);
        }
    }
}

// thread-per-row GEMV for tiny F (layer 3: K=50, F=6), fp32 out stride FS.
template <int K, int F, int FS, bool RELU_IN>
__global__ __launch_bounds__(256) void gemv_rows_kernel(const float* __restrict__ X,
                                                        const float* __restrict__ W,
                                                        float* __restrict__ H, int n) {
    static_assert(K % 2 == 0, "K must be even");
    __shared__ float Ws[K * F];
    const int tid = threadIdx.x;
    for (int i = tid; i < K * F; i += 256) Ws[i] = W[i];
    __syncthreads();
    int r = blockIdx.x * 256 + tid;
    if (r >= n) return;
    float acc[F] = {};
    const float* xp = X + (long long)r * K;
    for (int k = 0; k < K; k += 2) {
        float2 x2 = *reinterpret_cast<const float2*>(xp + k);
        if (RELU_IN) { x2.x = fmaxf(x2.x, 0.f); x2.y = fmaxf(x2.y, 0.f); }
#pragma unroll
        for (int j = 0; j < F; ++j)
            acc[j] += x2.x * Ws[k * F + j] + x2.y * Ws[(k + 1) * F + j];
    }
    long long base = (long long)r * FS;
#pragma unroll
    for (int j = 0; j < F; ++j) H[base + j] = acc[j];
}

// ---------------- single-pass agg, 256B bf16 rows, uint4 lanes ----------------
// Output: bf16 A-rows (RSOUT ushorts, 256B) with fused ReLU - feeds MFMA GEMM.
// R17: fully-pad lanes (f>=F) return BEFORE the gather loop (R15 wasted 19%
// of gather requests on them); 8-deep edge pipeline (2x MLP vs R15's 4);
// nontemporal epack loads. Pad cols f..f+7 beyond F: o[k]=0 for k>=valid;
// cols on fully-dead lanes stay poison, neutralized by zeroed W pad rows.
template <int F, int RSIN, int RSOUT>
__global__ __launch_bounds__(BT) void agg_o4_kernel(const int* __restrict__ rowptr,
                                                    const int* __restrict__ perm,
                                                    const long long* __restrict__ epack,
                                                    const uint4* __restrict__ H,
                                                    const float* __restrict__ dis,
                                                    const float* __restrict__ bias,
                                                    unsigned short* __restrict__ A, int n) {
    constexpr int TPN = 16, NPB = BT / TPN;
    constexpr int RU4 = RSIN / 8;
    const int sidx = blockIdx.x * NPB + threadIdx.x / TPN;
    const int lane = threadIdx.x & (TPN - 1);
    if (sidx >= n) return;
    const int f = 8 * lane;
    if (f >= F) return;  // fully-pad lane: no gather work at all
    const int node = perm[sidx];

    float a[8] = {};
    int j = rowptr[node];
    const int end = rowptr[node + 1];
    for (; j + 8 <= end; j += 8) {
        long long e[8];
        uint4 v[8];
#pragma unroll
        for (int t = 0; t < 8; ++t) e[t] = __builtin_nontemporal_load(&epack[j + t]);
#pragma unroll
        for (int t = 0; t < 8; ++t) v[t] = H[(size_t)(int)e[t] * RU4 + lane];
#pragma unroll
        for (int t = 0; t < 8; ++t) {
            float nv = __int_as_float((int)(e[t] >> 32));
            a[0] += nv * bf_lo(v[t].x); a[1] += nv * bf_hi(v[t].x);
            a[2] += nv * bf_lo(v[t].y); a[3] += nv * bf_hi(v[t].y);
            a[4] += nv * bf_lo(v[t].z); a[5] += nv * bf_hi(v[t].z);
            a[6] += nv * bf_lo(v[t].w); a[7] += nv * bf_hi(v[t].w);
        }
    }
    for (; j < end; ++j) {
        long long ev = __builtin_nontemporal_load(&epack[j]);
        uint4 v = H[(size_t)(int)ev * RU4 + lane];
        float nv = __int_as_float((int)(ev >> 32));
        a[0] += nv * bf_lo(v.x); a[1] += nv * bf_hi(v.x);
        a[2] += nv * bf_lo(v.y); a[3] += nv * bf_hi(v.y);
        a[4] += nv * bf_lo(v.z); a[5] += nv * bf_hi(v.z);
        a[6] += nv * bf_lo(v.w); a[7] += nv * bf_hi(v.w);
    }
    const int valid = F - f;  // >= 1 here
    float d = dis[node];
    float d2 = d * d;
    uint4 hs = H[(size_t)node * RU4 + lane];
    float h[8] = {bf_lo(hs.x), bf_hi(hs.x), bf_lo(hs.y), bf_hi(hs.y),
                  bf_lo(hs.z), bf_hi(hs.z), bf_lo(hs.w), bf_hi(hs.w)};
    unsigned short o[8];
#pragma unroll
    for (int k = 0; k < 8; ++k) {
        float t = (k < valid) ? fmaxf(bias[f + k] + d2 * h[k] + a[k], 0.f) : 0.f;
        o[k] = f2bf(t);
    }
    nuint4 qv;
    qv.x = ((unsigned int)o[1] << 16) | o[0];
    qv.y = ((unsigned int)o[3] << 16) | o[2];
    qv.z = ((unsigned int)o[5] << 16) | o[4];
    qv.w = ((unsigned int)o[7] << 16) | o[6];
    __builtin_nontemporal_store(qv, (nuint4*)&A[(size_t)node * RSOUT + f]);
}

// single-pass agg, 128B bf16 rows in, fp32 out (layer 2 -> gemv). f = 4*lane.
template <int F, int RSIN>
__global__ __launch_bounds__(BT) void agg_u2_kernel(const int* __restrict__ rowptr,
                                                    const int* __restrict__ perm,
                                                    const long long* __restrict__ epack,
                                                    const uint2* __restrict__ H,
                                                    const float* __restrict__ dis,
                                                    const float* __restrict__ bias,
                                                    float* __restrict__ A, int n) {
    constexpr int TPN = 16, NPB = BT / TPN;
    constexpr int RU2 = RSIN / 4;
    const int sidx = blockIdx.x * NPB + threadIdx.x / TPN;
    const int lane = threadIdx.x & (TPN - 1);
    if (sidx >= n) return;
    const int f = 4 * lane;
    if (f >= F) return;  // fully-pad lane: skip gather entirely
    const int node = perm[sidx];

    float a0 = 0.f, a1 = 0.f, a2 = 0.f, a3 = 0.f;
    int j = rowptr[node];
    const int end = rowptr[node + 1];
    for (; j + 8 <= end; j += 8) {
        long long e[8];
        uint2 v[8];
#pragma unroll
        for (int t = 0; t < 8; ++t) e[t] = __builtin_nontemporal_load(&epack[j + t]);
#pragma unroll
        for (int t = 0; t < 8; ++t) v[t] = H[(size_t)(int)e[t] * RU2 + lane];
#pragma unroll
        for (int t = 0; t < 8; ++t) {
            float nv = __int_as_float((int)(e[t] >> 32));
            a0 += nv * bf_lo(v[t].x); a1 += nv * bf_hi(v[t].x);
            a2 += nv * bf_lo(v[t].y); a3 += nv * bf_hi(v[t].y);
        }
    }
    for (; j < end; ++j) {
        long long ev = __builtin_nontemporal_load(&epack[j]);
        uint2 v = H[(size_t)(int)ev * RU2 + lane];
        float nv = __int_as_float((int)(ev >> 32));
        a0 += nv * bf_lo(v.x); a1 += nv * bf_hi(v.x);
        a2 += nv * bf_lo(v.y); a3 += nv * bf_hi(v.y);
    }
    float d = dis[node];
    float d2 = d * d;
    uint2 hs = H[(size_t)node * RU2 + lane];
    float o0 = 0.f, o1 = 0.f, o2 = 0.f, o3 = 0.f;
    if (f < F) o0 = bias[f] + d2 * bf_lo(hs.x) + a0;
    if (f + 1 < F) o1 = bias[f + 1] + d2 * bf_hi(hs.x) + a1;
    if (f + 2 < F) o2 = bias[f + 2] + d2 * bf_lo(hs.y) + a2;
    if (f + 3 < F) o3 = bias[f + 3] + d2 * bf_hi(hs.y) + a3;
    float* ap = &A[(size_t)node * F + f];
    if (f + 3 < F) {
        nfloat4 q = {o0, o1, o2, o3};
        __builtin_nontemporal_store(q, (nfloat4*)ap);
    } else if (f + 1 < F) {  // F=50 tail at f=48
        nfloat2 q = {o0, o1};
        __builtin_nontemporal_store(q, (nfloat2*)ap);
    } else {
        __builtin_nontemporal_store(o0, ap);
    }
}

// per-node agg for tiny F (fp32 H, row stride 8), degree-sorted
template <int F, int TPN>
__global__ __launch_bounds__(BT) void agg_small_kernel(const int* __restrict__ rowptr,
                                                       const int* __restrict__ perm,
                                                       const long long* __restrict__ epack,
                                                       const float* __restrict__ H,
                                                       const float* __restrict__ dis,
                                                       const float* __restrict__ bias,
                                                       float* __restrict__ A, int n) {
    int gid = blockIdx.x * blockDim.x + threadIdx.x;
    int sidx = gid / TPN;
    int lane = threadIdx.x & (TPN - 1);
    if (sidx >= n) return;
    int node = perm[sidx];
    bool active = (lane < F);
    float acc = 0.f;
    int j = rowptr[node];
    const int end = rowptr[node + 1];
    for (; j + 4 <= end; j += 4) {
        long long e0 = epack[j + 0];
        long long e1 = epack[j + 1];
        long long e2 = epack[j + 2];
        long long e3 = epack[j + 3];
        if (active) {
            float h0 = H[(size_t)(int)e0 * 8 + lane];
            float h1 = H[(size_t)(int)e1 * 8 + lane];
            float h2 = H[(size_t)(int)e2 * 8 + lane];
            float h3 = H[(size_t)(int)e3 * 8 + lane];
            acc += __int_as_float((int)(e0 >> 32)) * h0;
            acc += __int_as_float((int)(e1 >> 32)) * h1;
            acc += __int_as_float((int)(e2 >> 32)) * h2;
            acc += __int_as_float((int)(e3 >> 32)) * h3;
        }
    }
    for (; j < end; ++j) {
        long long ev = epack[j];
        if (active) acc += __int_as_float((int)(ev >> 32)) * H[(size_t)(int)ev * 8 + lane];
    }
    if (active) {
        float d = dis[node];
        float v = bias[lane] + d * d * H[(size_t)node * 8 + lane] + acc;
        __builtin_nontemporal_store(v, &A[(size_t)node * F + lane]);
    }
}

// ---------------------------------------------------------------------------
extern "C" void kernel_launch(void* const* d_in, const int* in_sizes, int n_in,
                              void* d_out, int out_size, void* d_ws, size_t ws_size,
                              hipStream_t stream) {
    const float* x  = (const float*)d_in[0];
    const int*   ei = (const int*)d_in[1];
    const float* ew = (const float*)d_in[2];
    const float* W0 = (const float*)d_in[3];
    const float* b0 = (const float*)d_in[4];
    const float* W1 = (const float*)d_in[5];
    const float* b1 = (const float*)d_in[6];
    const float* W2 = (const float*)d_in[7];
    const float* b2 = (const float*)d_in[8];
    const float* W3 = (const float*)d_in[9];
    const float* b3 = (const float*)d_in[10];
    float* out = (float*)d_out;

    const int N = in_sizes[0] / 128;  // 50000
    const int E = in_sizes[1] / 2;    // 800000
    const int* row = ei;
    const int* col = ei + E;

    const int NB = (N + SCAN_B - 1) / SCAN_B;
    const int blocksN = (N + BT - 1) / BT;
    const int blocksE = (E + BT - 1) / BT;

    // workspace, 64B-aligned sections
    char* p = (char*)d_ws;
    auto alloc = [&](size_t bytes) {
        p = (char*)(((uintptr_t)p + 63) & ~(uintptr_t)63);
        void* r = (void*)p;
        p += bytes;
        return r;
    };
    float* dis    = (float*)alloc((size_t)N * 4);
    int*   rowptr = (int*)alloc((size_t)(N + 2) * 4);
    int*   bsums  = (int*)alloc(SCAN_B * 4);
    unsigned int* cw = (unsigned int*)alloc((size_t)(N + 256) * 4);  // cw[N] + dbin[256]
    int*   dbin   = (int*)(cw + N);
    int*   nrank  = (int*)alloc((size_t)N * 4);
    int*   perm   = (int*)alloc((size_t)N * 4);
    int*   rank   = (int*)alloc((size_t)E * 4);
    long long* epack = (long long*)alloc((size_t)E * 8);
    unsigned short* bufA = (unsigned short*)alloc((size_t)N * 128 * 2);  // H bf16, 256B rows
    unsigned short* bufB = (unsigned short*)alloc((size_t)N * 128 * 2);  // A bf16 / A3 fp32
    float* bufAf  = (float*)bufA;  // layer-3 fp32 H3[N,8] aliases bufA
    float* bufBf  = (float*)bufB;  // layer-3 fp32 A3[N,50] aliases bufB

    // ---- CSR + norm + degree-sort precompute ----
    zero_kernel<<<(N + 256 + BT - 1) / BT, BT, 0, stream>>>(cw, N + 256);
    hist_kernel<<<blocksE, BT, 0, stream>>>(row, ew, cw, rank, E);
    nodeprep_kernel<<<NB, SCAN_B, 0, stream>>>(cw, rowptr, bsums, dis, dbin, nrank, N);
    scan2both_kernel<<<1, 256, 0, stream>>>(bsums, NB, dbin);
    scan3_kernel<<<blocksN, BT, 0, stream>>>(rowptr, bsums, cw, nrank, dbin, perm, N, E);
    fill_kernel<<<blocksE, BT, 0, stream>>>(row, col, ew, dis, rowptr, rank, epack, E);

    const int gemm_blocks = (N + 63) / 64;   // 64 rows/block (4 waves x 16)
    const int agg_blocks  = (N + 15) / 16;   // 16 nodes/block
    const int agg6_blocks = (N * 8 + BT - 1) / BT;

    // ---- layer 0: x fp32 (K=128) -> H bf16 100(112) cols ----
    gemm_mfma_kernel<128, 128, 100, false, 128, 128><<<gemm_blocks, 256, 0, stream>>>(x, W0, bufA, N);
    agg_o4_kernel<100, 128, 128><<<agg_blocks, BT, 0, stream>>>(rowptr, perm, epack, (const uint4*)bufA, dis, b0, bufB, N);

    // ---- layer 1: A1 bf16 (K=100 pad 128) -> H bf16 ----
    gemm_mfma_kernel<100, 128, 100, true, 128, 128><<<gemm_blocks, 256, 0, stream>>>(bufB, W1, bufA, N);
    agg_o4_kernel<100, 128, 128><<<agg_blocks, BT, 0, stream>>>(rowptr, perm, epack, (const uint4*)bufA, dis, b1, bufB, N);

    // ---- layer 2: A2 bf16 -> H bf16 50(64) cols, then agg to fp32 A3 ----
    gemm_mfma_kernel<100, 128, 50, true, 128, 64><<<gemm_blocks, 256, 0, stream>>>(bufB, W2, bufA, N);
    agg_u2_kernel<50, 64><<<agg_blocks, BT, 0, stream>>>(rowptr, perm, epack, (const uint2*)bufA, dis, b2, bufBf, N);

    // ---- layer 3: gemv (relu on load) + small agg ----
    gemv_rows_kernel<50, 6, 8, true><<<(N + 255) / 256, 256, 0, stream>>>(bufBf, W3, bufAf, N);
    agg_small_kernel<6, 8><<<agg6_blocks, BT, 0, stream>>>(rowptr, perm, epack, bufAf, dis, b3, out, N);
}

// Round 4
// 332.890 us; speedup vs baseline: 1.2031x; 1.0537x over previous
//
#include <hip/hip_runtime.h>

// ---------------------------------------------------------------------------
// GCN forward. Evidence-driven design (R4-R19):
//  - GEMMs on MFMA (16x16x32 bf16): W staged in LDS pre-swizzled to B-frag
//    layout; A-frag = one 16B bf16 load; C/D: row=(lane>>4)*4+reg, col=lane&15.
//    K padded to 128; zeroed W pad rows neutralize garbage in A pad cols.
//  - R16 POST-MORTEM: feature-sliced H (4 x 64B planes, XCD-pinned) REGRESSED
//    333->400us (line traffic doubled: 4 half-used 128B lines/edge vs 2 full).
//    256B-aligned rows are already at the 4-sector/edge floor. REVERTED.
//  - R18 POST-MORTEM (333->351): NT epack loads were the bug. epack is read
//    16x per 128B line (16 edges/line, 8B at a time by one thread); regular
//    loads hit L1 15/16 times, NT (no-allocate) degraded those hits to
//    fabric accesses AND added latency at the head of the epack->H dependent
//    chain. R19 reverts epack loads to cached; NT kept ONLY for write-only
//    output streams. Kept from R17: pad-lane early-return (removes 19% of
//    gather requests, zero traffic change) and 8-deep gather pipeline (MLP).
//  - agg: single pass, 256B bf16 rows, TPN=16 x uint4 (8 feats/lane);
//    degree-sorted perm (hierarchical LDS histogram).
//  - ONE packed 32-bit atomic per edge (count<<24|wsum fix16); returned rank
//    makes CSR fill atomic-free. edge (col,norm) packed i64; NT stores.
// ---------------------------------------------------------------------------

#define BT 256
#define SCAN_B 256

typedef float nfloat4 __attribute__((ext_vector_type(4)));
typedef float nfloat2 __attribute__((ext_vector_type(2)));
typedef unsigned int nuint4 __attribute__((ext_vector_type(4)));
typedef __attribute__((ext_vector_type(8))) short shortx8;   // 8 bf16 (A/B frag)
typedef __attribute__((ext_vector_type(4))) float floatx4;   // C/D frag

__device__ inline float bf_lo(unsigned int v) { return __uint_as_float(v << 16); }
__device__ inline float bf_hi(unsigned int v) { return __uint_as_float(v & 0xFFFF0000u); }
__device__ inline unsigned short f2bf(float f) {  // round-to-nearest-even
    unsigned int u = __float_as_uint(f);
    unsigned int r = u + 0x7FFFu + ((u >> 16) & 1u);
    return (unsigned short)(r >> 16);
}

// ---------------- precompute ----------------
__global__ void zero_kernel(unsigned int* buf, int n) {
    int i = blockIdx.x * blockDim.x + threadIdx.x;
    if (i < n) buf[i] = 0u;
}

__global__ void hist_kernel(const int* __restrict__ row, const float* __restrict__ w,
                            unsigned int* cw, int* __restrict__ rank, int e) {
    int i = blockIdx.x * blockDim.x + threadIdx.x;
    if (i >= e) return;
    unsigned int wq = (unsigned int)(w[i] * 65536.0f + 0.5f);
    unsigned int old = atomicAdd(&cw[row[i]], (1u << 24) | wq);
    rank[i] = (int)(old >> 24);
}

// FUSED: block-scan of counts + dis + hierarchical degree histogram
__global__ __launch_bounds__(SCAN_B) void nodeprep_kernel(const unsigned int* __restrict__ cw,
                                                          int* rowptr, int* bsums, float* dis,
                                                          int* dbin, int* __restrict__ nrank,
                                                          int n) {
    __shared__ int s[SCAN_B];
    __shared__ int lbin[256];
    __shared__ int lbase[256];
    const int t = threadIdx.x;
    const int i = blockIdx.x * SCAN_B + t;
    unsigned int cv = (i < n) ? cw[i] : 0u;
    const int v = (int)(cv >> 24);
    lbin[t] = 0;
    s[t] = v;
    __syncthreads();
    int lr = 0;
    if (i < n) lr = atomicAdd(&lbin[v], 1);
    __syncthreads();
    for (int off = 1; off < SCAN_B; off <<= 1) {
        int x = (t >= off) ? s[t - off] : 0;
        __syncthreads();
        s[t] += x;
        __syncthreads();
    }
    if (i < n) {
        rowptr[i] = s[t] - v;
        float d = 1.0f + (float)(cv & 0xFFFFFFu) * (1.0f / 65536.0f);
        dis[i] = rsqrtf(fmaxf(d, 1e-12f));
    }
    if (t == SCAN_B - 1) bsums[blockIdx.x] = s[t];
    int c = lbin[t];
    lbase[t] = (c > 0) ? atomicAdd(&dbin[t], c) : 0;
    __syncthreads();
    if (i < n) nrank[i] = lbase[v] + lr;
}

__global__ __launch_bounds__(256) void scan2both_kernel(int* bsums, int nb, int* dbin) {
    __shared__ int s[256];
    const int t = threadIdx.x;
    int v = (t < nb) ? bsums[t] : 0;
    s[t] = v;
    __syncthreads();
    for (int off = 1; off < 256; off <<= 1) {
        int x = (t >= off) ? s[t - off] : 0;
        __syncthreads();
        s[t] += x;
        __syncthreads();
    }
    if (t < nb) bsums[t] = s[t] - v;
    __syncthreads();
    int v2 = dbin[t];
    s[t] = v2;
    __syncthreads();
    for (int off = 1; off < 256; off <<= 1) {
        int x = (t >= off) ? s[t - off] : 0;
        __syncthreads();
        s[t] += x;
        __syncthreads();
    }
    dbin[t] = s[t] - v2;
}

__global__ void scan3_kernel(int* rowptr, const int* __restrict__ bsums,
                             const unsigned int* __restrict__ cw,
                             const int* __restrict__ nrank, const int* __restrict__ dbin,
                             int* __restrict__ perm, int n, int e) {
    int i = blockIdx.x * blockDim.x + threadIdx.x;
    if (i < n) {
        rowptr[i] += bsums[i / SCAN_B];
        unsigned int deg = cw[i] >> 24;
        perm[dbin[deg] + nrank[i]] = i;
    }
    if (i == 0) rowptr[n] = e;
}

__global__ void fill_kernel(const int* __restrict__ row, const int* __restrict__ col,
                            const float* __restrict__ w, const float* __restrict__ dis,
                            const int* __restrict__ rowptr, const int* __restrict__ rank,
                            long long* __restrict__ epack, int e) {
    int i = blockIdx.x * blockDim.x + threadIdx.x;
    if (i >= e) return;
    int r = row[i], c = col[i];
    float nv = dis[r] * w[i] * dis[c];
    int dst = rowptr[r] + rank[i];
    long long v = ((long long)__float_as_int(nv) << 32) | (unsigned int)c;
    __builtin_nontemporal_store(v, &epack[dst]);
}

// ---------------- MFMA GEMM: H(bf16, OUTS-stride rows) = X @ W --------------
template <int KREAL, int KPAD, int F, bool IN_BF16, int INS, int OUTS>
__global__ __launch_bounds__(256) void gemm_mfma_kernel(const void* __restrict__ Xv,
                                                        const float* __restrict__ W,
                                                        unsigned short* __restrict__ H, int n) {
    constexpr int KS = KPAD / 32;
    constexpr int NT = (F + 15) / 16;
    __shared__ unsigned short Wf[KS * NT * 64 * 8];
    const int tid = threadIdx.x;
    for (int i = tid; i < KS * NT * 64 * 8; i += 256) {
        int j = i & 7;
        int ln = (i >> 3) & 63;
        int rest = i >> 9;
        int nt = rest % NT;
        int ks = rest / NT;
        int k = ks * 32 + ((ln >> 4) << 3) + j;
        int c = nt * 16 + (ln & 15);
        float wv = (k < KREAL && c < F) ? W[k * F + c] : 0.f;
        Wf[i] = f2bf(wv);
    }
    __syncthreads();

    const int wid = tid >> 6;
    const int lane = tid & 63;
    const int m = lane & 15;
    const int q = lane >> 4;
    const int r0 = blockIdx.x * 64 + wid * 16;
    int rowc = r0 + m;
    if (rowc > n - 1) rowc = n - 1;  // clamp loads; stores guarded

    floatx4 acc[NT];
#pragma unroll
    for (int nt = 0; nt < NT; ++nt) acc[nt] = (floatx4){0.f, 0.f, 0.f, 0.f};

    const float* Xf = (const float*)Xv;
    const unsigned short* Xb = (const unsigned short*)Xv;
#pragma unroll
    for (int ks = 0; ks < KS; ++ks) {
        shortx8 af;
        if constexpr (IN_BF16) {
            af = *(const shortx8*)&Xb[(size_t)rowc * INS + ks * 32 + q * 8];
        } else {
            const float* xp = &Xf[(size_t)rowc * INS + ks * 32 + q * 8];
            float4 xa = *(const float4*)xp;
            float4 xc = *(const float4*)(xp + 4);
            union { shortx8 s; unsigned int u[4]; } cv;
            cv.u[0] = ((unsigned int)f2bf(xa.y) << 16) | f2bf(xa.x);
            cv.u[1] = ((unsigned int)f2bf(xa.w) << 16) | f2bf(xa.z);
            cv.u[2] = ((unsigned int)f2bf(xc.y) << 16) | f2bf(xc.x);
            cv.u[3] = ((unsigned int)f2bf(xc.w) << 16) | f2bf(xc.z);
            af = cv.s;
        }
#pragma unroll
        for (int nt = 0; nt < NT; ++nt) {
            shortx8 bf = *(const shortx8*)&Wf[(((ks * NT) + nt) * 64 + lane) * 8];
            acc[nt] = __builtin_amdgcn_mfma_f32_16x16x32_bf16(af, bf, acc[nt], 0, 0, 0);
        }
    }

#pragma unroll
    for (int nt = 0; nt < NT; ++nt) {
        int c = nt * 16 + m;
        if (c >= F) continue;
#pragma unroll
        for (int r = 0; r < 4; ++r) {
            int orow = r0 + q * 4 + r;
            if (orow < n) H[(size_t)orow * OUTS + c] = f2bf(acc[nt][r]);
        }
    }
}

// thread-per-row GEMV for tiny F (layer 3: K=50, F=6), fp32 out stride FS.
template <int K, int F, int FS, bool RELU_IN>
__global__ __launch_bounds__(256) void gemv_rows_kernel(const float* __restrict__ X,
                                                        const float* __restrict__ W,
                                                        float* __restrict__ H, int n) {
    static_assert(K % 2 == 0, "K must be even");
    __shared__ float Ws[K * F];
    const int tid = threadIdx.x;
    for (int i = tid; i < K * F; i += 256) Ws[i] = W[i];
    __syncthreads();
    int r = blockIdx.x * 256 + tid;
    if (r >= n) return;
    float acc[F] = {};
    const float* xp = X + (long long)r * K;
    for (int k = 0; k < K; k += 2) {
        float2 x2 = *reinterpret_cast<const float2*>(xp + k);
        if (RELU_IN) { x2.x = fmaxf(x2.x, 0.f); x2.y = fmaxf(x2.y, 0.f); }
#pragma unroll
        for (int j = 0; j < F; ++j)
            acc[j] += x2.x * Ws[k * F + j] + x2.y * Ws[(k + 1) * F + j];
    }
    long long base = (long long)r * FS;
#pragma unroll
    for (int j = 0; j < F; ++j) H[base + j] = acc[j];
}

// ---------------- single-pass agg, 256B bf16 rows, uint4 lanes ----------------
// Output: bf16 A-rows (RSOUT ushorts, 256B) with fused ReLU - feeds MFMA GEMM.
// Pad lanes (f>=F) return BEFORE the gather loop; 8-deep edge pipeline;
// epack loads CACHED (R19: 16 edges share each 128B line -> L1 hits).
template <int F, int RSIN, int RSOUT>
__global__ __launch_bounds__(BT) void agg_o4_kernel(const int* __restrict__ rowptr,
                                                    const int* __restrict__ perm,
                                                    const long long* __restrict__ epack,
                                                    const uint4* __restrict__ H,
                                                    const float* __restrict__ dis,
                                                    const float* __restrict__ bias,
                                                    unsigned short* __restrict__ A, int n) {
    constexpr int TPN = 16, NPB = BT / TPN;
    constexpr int RU4 = RSIN / 8;
    const int sidx = blockIdx.x * NPB + threadIdx.x / TPN;
    const int lane = threadIdx.x & (TPN - 1);
    if (sidx >= n) return;
    const int f = 8 * lane;
    if (f >= F) return;  // fully-pad lane: no gather work at all
    const int node = perm[sidx];

    float a[8] = {};
    int j = rowptr[node];
    const int end = rowptr[node + 1];
    for (; j + 8 <= end; j += 8) {
        long long e[8];
        uint4 v[8];
#pragma unroll
        for (int t = 0; t < 8; ++t) e[t] = epack[j + t];
#pragma unroll
        for (int t = 0; t < 8; ++t) v[t] = H[(size_t)(int)e[t] * RU4 + lane];
#pragma unroll
        for (int t = 0; t < 8; ++t) {
            float nv = __int_as_float((int)(e[t] >> 32));
            a[0] += nv * bf_lo(v[t].x); a[1] += nv * bf_hi(v[t].x);
            a[2] += nv * bf_lo(v[t].y); a[3] += nv * bf_hi(v[t].y);
            a[4] += nv * bf_lo(v[t].z); a[5] += nv * bf_hi(v[t].z);
            a[6] += nv * bf_lo(v[t].w); a[7] += nv * bf_hi(v[t].w);
        }
    }
    for (; j < end; ++j) {
        long long ev = epack[j];
        uint4 v = H[(size_t)(int)ev * RU4 + lane];
        float nv = __int_as_float((int)(ev >> 32));
        a[0] += nv * bf_lo(v.x); a[1] += nv * bf_hi(v.x);
        a[2] += nv * bf_lo(v.y); a[3] += nv * bf_hi(v.y);
        a[4] += nv * bf_lo(v.z); a[5] += nv * bf_hi(v.z);
        a[6] += nv * bf_lo(v.w); a[7] += nv * bf_hi(v.w);
    }
    const int valid = F - f;  // >= 1 here
    float d = dis[node];
    float d2 = d * d;
    uint4 hs = H[(size_t)node * RU4 + lane];
    float h[8] = {bf_lo(hs.x), bf_hi(hs.x), bf_lo(hs.y), bf_hi(hs.y),
                  bf_lo(hs.z), bf_hi(hs.z), bf_lo(hs.w), bf_hi(hs.w)};
    unsigned short o[8];
#pragma unroll
    for (int k = 0; k < 8; ++k) {
        float t = (k < valid) ? fmaxf(bias[f + k] + d2 * h[k] + a[k], 0.f) : 0.f;
        o[k] = f2bf(t);
    }
    nuint4 qv;
    qv.x = ((unsigned int)o[1] << 16) | o[0];
    qv.y = ((unsigned int)o[3] << 16) | o[2];
    qv.z = ((unsigned int)o[5] << 16) | o[4];
    qv.w = ((unsigned int)o[7] << 16) | o[6];
    __builtin_nontemporal_store(qv, (nuint4*)&A[(size_t)node * RSOUT + f]);
}

// single-pass agg, 128B bf16 rows in, fp32 out (layer 2 -> gemv). f = 4*lane.
template <int F, int RSIN>
__global__ __launch_bounds__(BT) void agg_u2_kernel(const int* __restrict__ rowptr,
                                                    const int* __restrict__ perm,
                                                    const long long* __restrict__ epack,
                                                    const uint2* __restrict__ H,
                                                    const float* __restrict__ dis,
                                                    const float* __restrict__ bias,
                                                    float* __restrict__ A, int n) {
    constexpr int TPN = 16, NPB = BT / TPN;
    constexpr int RU2 = RSIN / 4;
    const int sidx = blockIdx.x * NPB + threadIdx.x / TPN;
    const int lane = threadIdx.x & (TPN - 1);
    if (sidx >= n) return;
    const int f = 4 * lane;
    if (f >= F) return;  // fully-pad lane: skip gather entirely
    const int node = perm[sidx];

    float a0 = 0.f, a1 = 0.f, a2 = 0.f, a3 = 0.f;
    int j = rowptr[node];
    const int end = rowptr[node + 1];
    for (; j + 8 <= end; j += 8) {
        long long e[8];
        uint2 v[8];
#pragma unroll
        for (int t = 0; t < 8; ++t) e[t] = epack[j + t];
#pragma unroll
        for (int t = 0; t < 8; ++t) v[t] = H[(size_t)(int)e[t] * RU2 + lane];
#pragma unroll
        for (int t = 0; t < 8; ++t) {
            float nv = __int_as_float((int)(e[t] >> 32));
            a0 += nv * bf_lo(v[t].x); a1 += nv * bf_hi(v[t].x);
            a2 += nv * bf_lo(v[t].y); a3 += nv * bf_hi(v[t].y);
        }
    }
    for (; j < end; ++j) {
        long long ev = epack[j];
        uint2 v = H[(size_t)(int)ev * RU2 + lane];
        float nv = __int_as_float((int)(ev >> 32));
        a0 += nv * bf_lo(v.x); a1 += nv * bf_hi(v.x);
        a2 += nv * bf_lo(v.y); a3 += nv * bf_hi(v.y);
    }
    float d = dis[node];
    float d2 = d * d;
    uint2 hs = H[(size_t)node * RU2 + lane];
    float o0 = 0.f, o1 = 0.f, o2 = 0.f, o3 = 0.f;
    if (f < F) o0 = bias[f] + d2 * bf_lo(hs.x) + a0;
    if (f + 1 < F) o1 = bias[f + 1] + d2 * bf_hi(hs.x) + a1;
    if (f + 2 < F) o2 = bias[f + 2] + d2 * bf_lo(hs.y) + a2;
    if (f + 3 < F) o3 = bias[f + 3] + d2 * bf_hi(hs.y) + a3;
    float* ap = &A[(size_t)node * F + f];
    if (f + 3 < F) {
        nfloat4 q = {o0, o1, o2, o3};
        __builtin_nontemporal_store(q, (nfloat4*)ap);
    } else if (f + 1 < F) {  // F=50 tail at f=48
        nfloat2 q = {o0, o1};
        __builtin_nontemporal_store(q, (nfloat2*)ap);
    } else {
        __builtin_nontemporal_store(o0, ap);
    }
}

// per-node agg for tiny F (fp32 H, row stride 8), degree-sorted
template <int F, int TPN>
__global__ __launch_bounds__(BT) void agg_small_kernel(const int* __restrict__ rowptr,
                                                       const int* __restrict__ perm,
                                                       const long long* __restrict__ epack,
                                                       const float* __restrict__ H,
                                                       const float* __restrict__ dis,
                                                       const float* __restrict__ bias,
                                                       float* __restrict__ A, int n) {
    int gid = blockIdx.x * blockDim.x + threadIdx.x;
    int sidx = gid / TPN;
    int lane = threadIdx.x & (TPN - 1);
    if (sidx >= n) return;
    int node = perm[sidx];
    bool active = (lane < F);
    float acc = 0.f;
    int j = rowptr[node];
    const int end = rowptr[node + 1];
    for (; j + 4 <= end; j += 4) {
        long long e0 = epack[j + 0];
        long long e1 = epack[j + 1];
        long long e2 = epack[j + 2];
        long long e3 = epack[j + 3];
        if (active) {
            float h0 = H[(size_t)(int)e0 * 8 + lane];
            float h1 = H[(size_t)(int)e1 * 8 + lane];
            float h2 = H[(size_t)(int)e2 * 8 + lane];
            float h3 = H[(size_t)(int)e3 * 8 + lane];
            acc += __int_as_float((int)(e0 >> 32)) * h0;
            acc += __int_as_float((int)(e1 >> 32)) * h1;
            acc += __int_as_float((int)(e2 >> 32)) * h2;
            acc += __int_as_float((int)(e3 >> 32)) * h3;
        }
    }
    for (; j < end; ++j) {
        long long ev = epack[j];
        if (active) acc += __int_as_float((int)(ev >> 32)) * H[(size_t)(int)ev * 8 + lane];
    }
    if (active) {
        float d = dis[node];
        float v = bias[lane] + d * d * H[(size_t)node * 8 + lane] + acc;
        __builtin_nontemporal_store(v, &A[(size_t)node * F + lane]);
    }
}

// ---------------------------------------------------------------------------
extern "C" void kernel_launch(void* const* d_in, const int* in_sizes, int n_in,
                              void* d_out, int out_size, void* d_ws, size_t ws_size,
                              hipStream_t stream) {
    const float* x  = (const float*)d_in[0];
    const int*   ei = (const int*)d_in[1];
    const float* ew = (const float*)d_in[2];
    const float* W0 = (const float*)d_in[3];
    const float* b0 = (const float*)d_in[4];
    const float* W1 = (const float*)d_in[5];
    const float* b1 = (const float*)d_in[6];
    const float* W2 = (const float*)d_in[7];
    const float* b2 = (const float*)d_in[8];
    const float* W3 = (const float*)d_in[9];
    const float* b3 = (const float*)d_in[10];
    float* out = (float*)d_out;

    const int N = in_sizes[0] / 128;  // 50000
    const int E = in_sizes[1] / 2;    // 800000
    const int* row = ei;
    const int* col = ei + E;

    const int NB = (N + SCAN_B - 1) / SCAN_B;
    const int blocksN = (N + BT - 1) / BT;
    const int blocksE = (E + BT - 1) / BT;

    // workspace, 64B-aligned sections
    char* p = (char*)d_ws;
    auto alloc = [&](size_t bytes) {
        p = (char*)(((uintptr_t)p + 63) & ~(uintptr_t)63);
        void* r = (void*)p;
        p += bytes;
        return r;
    };
    float* dis    = (float*)alloc((size_t)N * 4);
    int*   rowptr = (int*)alloc((size_t)(N + 2) * 4);
    int*   bsums  = (int*)alloc(SCAN_B * 4);
    unsigned int* cw = (unsigned int*)alloc((size_t)(N + 256) * 4);  // cw[N] + dbin[256]
    int*   dbin   = (int*)(cw + N);
    int*   nrank  = (int*)alloc((size_t)N * 4);
    int*   perm   = (int*)alloc((size_t)N * 4);
    int*   rank   = (int*)alloc((size_t)E * 4);
    long long* epack = (long long*)alloc((size_t)E * 8);
    unsigned short* bufA = (unsigned short*)alloc((size_t)N * 128 * 2);  // H bf16, 256B rows
    unsigned short* bufB = (unsigned short*)alloc((size_t)N * 128 * 2);  // A bf16 / A3 fp32
    float* bufAf  = (float*)bufA;  // layer-3 fp32 H3[N,8] aliases bufA
    float* bufBf  = (float*)bufB;  // layer-3 fp32 A3[N,50] aliases bufB

    // ---- CSR + norm + degree-sort precompute ----
    zero_kernel<<<(N + 256 + BT - 1) / BT, BT, 0, stream>>>(cw, N + 256);
    hist_kernel<<<blocksE, BT, 0, stream>>>(row, ew, cw, rank, E);
    nodeprep_kernel<<<NB, SCAN_B, 0, stream>>>(cw, rowptr, bsums, dis, dbin, nrank, N);
    scan2both_kernel<<<1, 256, 0, stream>>>(bsums, NB, dbin);
    scan3_kernel<<<blocksN, BT, 0, stream>>>(rowptr, bsums, cw, nrank, dbin, perm, N, E);
    fill_kernel<<<blocksE, BT, 0, stream>>>(row, col, ew, dis, rowptr, rank, epack, E);

    const int gemm_blocks = (N + 63) / 64;   // 64 rows/block (4 waves x 16)
    const int agg_blocks  = (N + 15) / 16;   // 16 nodes/block
    const int agg6_blocks = (N * 8 + BT - 1) / BT;

    // ---- layer 0: x fp32 (K=128) -> H bf16 100(112) cols ----
    gemm_mfma_kernel<128, 128, 100, false, 128, 128><<<gemm_blocks, 256, 0, stream>>>(x, W0, bufA, N);
    agg_o4_kernel<100, 128, 128><<<agg_blocks, BT, 0, stream>>>(rowptr, perm, epack, (const uint4*)bufA, dis, b0, bufB, N);

    // ---- layer 1: A1 bf16 (K=100 pad 128) -> H bf16 ----
    gemm_mfma_kernel<100, 128, 100, true, 128, 128><<<gemm_blocks, 256, 0, stream>>>(bufB, W1, bufA, N);
    agg_o4_kernel<100, 128, 128><<<agg_blocks, BT, 0, stream>>>(rowptr, perm, epack, (const uint4*)bufA, dis, b1, bufB, N);

    // ---- layer 2: A2 bf16 -> H bf16 50(64) cols, then agg to fp32 A3 ----
    gemm_mfma_kernel<100, 128, 50, true, 128, 64><<<gemm_blocks, 256, 0, stream>>>(bufB, W2, bufA, N);
    agg_u2_kernel<50, 64><<<agg_blocks, BT, 0, stream>>>(rowptr, perm, epack, (const uint2*)bufA, dis, b2, bufBf, N);

    // ---- layer 3: gemv (relu on load) + small agg ----
    gemv_rows_kernel<50, 6, 8, true><<<(N + 255) / 256, 256, 0, stream>>>(bufBf, W3, bufAf, N);
    agg_small_kernel<6, 8><<<agg6_blocks, BT, 0, stream>>>(rowptr, perm, epack, bufAf, dis, b3, out, N);
}